// Round 16
// baseline (432.281 us; speedup 1.0000x reference)
//
#include <hip/hip_runtime.h>

typedef __bf16 bf16x8 __attribute__((ext_vector_type(8)));
typedef __bf16 bf16x4 __attribute__((ext_vector_type(4)));
typedef float f32x4 __attribute__((ext_vector_type(4)));

constexpr int CC = 512;   // channels
constexpr int KK = 64;    // bases
constexpr int NN = 4096;  // h*w
constexpr int BB = 16;    // batch

// workspace layout (float units)
constexpr size_t R1_OFF    = 0;                     // XT bf16 [b][n][c]
constexpr size_t R2_OFF    = 16777216;              // XFT bf16 [b][n][c], later XRT bf16 [b][n][c]
constexpr size_t Z_OFF     = 33554432;              // Z  bf16 [b][n][k]
constexpr size_t ZT_OFF    = 35651584;              // ZT bf16 [b][k][n]
constexpr size_t MUACC_OFF = 37748736;              // fp32 [b][c][k]
constexpr size_t ZSUM_OFF  = 38273024;              // fp32 [b][k]
constexpr size_t MUBF_OFF  = 38274048;              // bf16 [b][c][k]
constexpr size_t MUTBF_OFF = 38536192;              // bf16 [b][k][c]
constexpr size_t W1BF_OFF  = 38798336;              // bf16 [o][c]
constexpr size_t W2BF_OFF  = 38929408;              // bf16 [o][c]
// XFC bf16 [b][c][n] lives in d_out (dead until conv2 writes the final output)

// ---------------- fp32 -> bf16 convert, both weight matrices in one launch ----------------
__global__ __launch_bounds__(256) void k_cvt2(const float* __restrict__ w1,
                                              const float* __restrict__ w2,
                                              __bf16* __restrict__ d1,
                                              __bf16* __restrict__ d2) {
    int blk = blockIdx.x;
    const float* src = (blk < 128) ? w1 : w2;
    __bf16* dst = (blk < 128) ? d1 : d2;
    int i = (blk & 127) * 256 + threadIdx.x;
    const float4* s4 = (const float4*)src;
    float4 a = s4[i * 2], b = s4[i * 2 + 1];
    bf16x8 o;
    o[0] = (__bf16)a.x; o[1] = (__bf16)a.y; o[2] = (__bf16)a.z; o[3] = (__bf16)a.w;
    o[4] = (__bf16)b.x; o[5] = (__bf16)b.y; o[6] = (__bf16)b.z; o[7] = (__bf16)b.w;
    *(bf16x8*)&dst[(size_t)i * 8] = o;
}

// ---------------- initial mu broadcast to both bf16 layouts ----------------
__global__ __launch_bounds__(256) void k_mu_bcast_bf(const float* __restrict__ mu_in,
                                                     __bf16* __restrict__ mu_bf,
                                                     __bf16* __restrict__ muT_bf) {
    int idx = blockIdx.x * 256 + threadIdx.x;
    if (idx < CC * KK) {
        int c = idx >> 6, k = idx & 63;
        __bf16 v = (__bf16)mu_in[idx];
        for (int b = 0; b < BB; ++b) {
            mu_bf[(size_t)b * CC * KK + idx] = v;
            muT_bf[((size_t)b * KK + k) * CC + c] = v;
        }
    }
}

// ---------------- X [b][c][n] fp32 -> XT [b][n][c] bf16 ----------------
__global__ __launch_bounds__(256) void k_xpose_cvt(const float* __restrict__ X,
                                                   __bf16* __restrict__ XT) {
    int n0 = blockIdx.x * 64, c0 = blockIdx.y * 64, b = blockIdx.z;
    __shared__ float T[64][65];
    int tid = threadIdx.x;
    const float* Xb = X + (size_t)b * CC * NN;
#pragma unroll
    for (int p = 0; p < 4; ++p) {
        int f4 = tid + p * 256;
        int row = f4 >> 4, col4 = (f4 & 15) * 4;
        float4 v = *(const float4*)&Xb[(size_t)(c0 + row) * NN + n0 + col4];
        T[row][col4 + 0] = v.x; T[row][col4 + 1] = v.y;
        T[row][col4 + 2] = v.z; T[row][col4 + 3] = v.w;
    }
    __syncthreads();
#pragma unroll
    for (int p = 0; p < 2; ++p) {
        int q = tid + p * 256;
        int nl = q >> 3, c8 = (q & 7) * 8;
        bf16x8 o;
#pragma unroll
        for (int j = 0; j < 8; ++j) o[j] = (__bf16)T[c8 + j][nl];
        *(bf16x8*)&XT[((size_t)b * NN + n0 + nl) * CC + c0 + c8] = o;
    }
}

// ---------------- conv1: 2-deep prefetch, 3-buffer LDS; XFT + XFC outputs ----------------
__global__ __launch_bounds__(256) void k_conv1_mfma(
    const __bf16* __restrict__ XT, const __bf16* __restrict__ W1,
    const float* __restrict__ bias, __bf16* __restrict__ XFT,
    __bf16* __restrict__ XFC) {
    __shared__ __bf16 SM[24576];     // As(3x4096) + Bs(3x4096); TT[128][136] aliases (17408 elems)
    __shared__ float sbias[128];
    __bf16* As = SM;                 // As[buf*4096 + w]
    __bf16* Bs = SM + 12288;
    int tid = threadIdx.x;
    int lane = tid & 63, wave = tid >> 6;
    int wm = wave >> 1, wn = wave & 1;
    int o0 = blockIdx.x * 128, n0 = blockIdx.y * 128, b = blockIdx.z;
    const __bf16* Ab = XT + ((size_t)b * NN + n0) * CC;
    const __bf16* Bb = W1 + (size_t)o0 * CC;
    if (tid < 128) sbias[tid] = bias[o0 + tid];

    f32x4 acc[4][4];
#pragma unroll
    for (int i = 0; i < 4; ++i)
#pragma unroll
        for (int j = 0; j < 4; ++j) acc[i][j] = f32x4{0.f, 0.f, 0.f, 0.f};

    int r0 = tid >> 2, k0c = tid & 3;
    int r1 = (tid + 256) >> 2, k1c = tid & 3;
    int w0 = r0 * 32 + (k0c ^ ((r0 >> 1) & 3)) * 8;
    int w1 = r1 * 32 + (k1c ^ ((r1 >> 1) & 3)) * 8;

    bf16x8 sa0, sa1, sb0, sb1;   // reg set 0
    bf16x8 ta0, ta1, tb0, tb1;   // reg set 1

    auto LD0 = [&](int kt) {
        const __bf16* Ak = Ab + kt * 32; const __bf16* Bk = Bb + kt * 32;
        sa0 = *(const bf16x8*)(Ak + (size_t)r0 * CC + k0c * 8);
        sa1 = *(const bf16x8*)(Ak + (size_t)r1 * CC + k1c * 8);
        sb0 = *(const bf16x8*)(Bk + (size_t)r0 * CC + k0c * 8);
        sb1 = *(const bf16x8*)(Bk + (size_t)r1 * CC + k1c * 8);
    };
    auto LD1 = [&](int kt) {
        const __bf16* Ak = Ab + kt * 32; const __bf16* Bk = Bb + kt * 32;
        ta0 = *(const bf16x8*)(Ak + (size_t)r0 * CC + k0c * 8);
        ta1 = *(const bf16x8*)(Ak + (size_t)r1 * CC + k1c * 8);
        tb0 = *(const bf16x8*)(Bk + (size_t)r0 * CC + k0c * 8);
        tb1 = *(const bf16x8*)(Bk + (size_t)r1 * CC + k1c * 8);
    };
    auto ST0 = [&](int buf) {
        *(bf16x8*)&As[buf * 4096 + w0] = sa0; *(bf16x8*)&As[buf * 4096 + w1] = sa1;
        *(bf16x8*)&Bs[buf * 4096 + w0] = sb0; *(bf16x8*)&Bs[buf * 4096 + w1] = sb1;
    };
    auto ST1 = [&](int buf) {
        *(bf16x8*)&As[buf * 4096 + w0] = ta0; *(bf16x8*)&As[buf * 4096 + w1] = ta1;
        *(bf16x8*)&Bs[buf * 4096 + w0] = tb0; *(bf16x8*)&Bs[buf * 4096 + w1] = tb1;
    };
    auto MMA = [&](int buf) {
        bf16x8 af[4], bg[4];
#pragma unroll
        for (int f = 0; f < 4; ++f) {
            int ra = wm * 64 + f * 16 + (lane & 15);
            af[f] = *(const bf16x8*)&As[buf * 4096 + ra * 32 + (((lane >> 4) ^ ((ra >> 1) & 3))) * 8];
            int rb = wn * 64 + f * 16 + (lane & 15);
            bg[f] = *(const bf16x8*)&Bs[buf * 4096 + rb * 32 + (((lane >> 4) ^ ((rb >> 1) & 3))) * 8];
        }
#pragma unroll
        for (int i = 0; i < 4; ++i)
#pragma unroll
            for (int j = 0; j < 4; ++j)
                acc[i][j] = __builtin_amdgcn_mfma_f32_16x16x32_bf16(af[i], bg[j], acc[i][j], 0, 0, 0);
    };

    // prologue: tile0 -> buf0; tile1 loads in flight (set1)
    LD0(0); ST0(0);
    LD1(1);
    __syncthreads();

    for (int kt = 0; kt < 16; kt += 2) {
        if (kt + 2 < 16) LD0(kt + 2);
        MMA(kt % 3);
        ST1((kt + 1) % 3);
        __syncthreads();
        if (kt + 3 < 16) LD1(kt + 3);
        MMA((kt + 1) % 3);
        if (kt + 2 < 16) ST0((kt + 2) % 3);
        __syncthreads();
    }

    // epilogue: XFC vectorized direct; XFT via LDS transpose tile TT[128n][136]
    __bf16* TT = SM;
    int gq = lane >> 4, ln = lane & 15;
#pragma unroll
    for (int mf = 0; mf < 4; ++mf) {
#pragma unroll
        for (int nf = 0; nf < 4; ++nf) {
            int o_loc = wn * 64 + nf * 16 + ln;
            int n_loc4 = wm * 64 + mf * 16 + gq * 4;
            float bi = sbias[o_loc];
            bf16x4 oc;
#pragma unroll
            for (int r = 0; r < 4; ++r) oc[r] = (__bf16)(acc[mf][nf][r] + bi);
            *(bf16x4*)&XFC[((size_t)b * CC + o0 + o_loc) * NN + n0 + n_loc4] = oc;
#pragma unroll
            for (int r = 0; r < 4; ++r) TT[(n_loc4 + r) * 136 + o_loc] = oc[r];
        }
    }
    __syncthreads();
#pragma unroll
    for (int p = 0; p < 8; ++p) {
        int idx = tid + p * 256;
        int row = idx >> 4, ch = idx & 15;
        bf16x8 v = *(const bf16x8*)&TT[row * 136 + ch * 8];
        *(bf16x8*)&XFT[((size_t)b * NN + n0 + row) * CC + o0 + ch * 8] = v;
    }
}

// ---------------- conv2: 256x128 tile, 8 waves, 2-deep prefetch, 3-buffer LDS ----------------
__global__ __launch_bounds__(512) void k_conv2_mfma(
    const __bf16* __restrict__ W2, const __bf16* __restrict__ XRT,
    const float* __restrict__ gamma, const float* __restrict__ beta,
    const float* __restrict__ mean, const float* __restrict__ var,
    const float* __restrict__ Xres, float* __restrict__ Out) {
    __shared__ __bf16 As[3][8192];   // XRT rows (n), 256 rows x 32
    __shared__ __bf16 Bs[3][4096];   // W2 rows (o), 128 rows x 32
    __shared__ float sp0[128], sp1[128];
    int tid = threadIdx.x;
    int lane = tid & 63, wave = tid >> 6;    // 8 waves
    int wm = wave >> 1, wn = wave & 1;       // wm 0..3 (n), wn 0..1 (o)
    int n0 = blockIdx.x * 256, m0 = blockIdx.y * 128, b = blockIdx.z;
    const __bf16* Ab = XRT + ((size_t)b * NN + n0) * CC;
    const __bf16* Bb = W2 + (size_t)m0 * CC;
    int gq = lane >> 4, ln = lane & 15;
    if (tid < 128) {
        float iv = gamma[m0 + tid] * rsqrtf(var[m0 + tid] + 1e-5f);
        sp0[tid] = iv;
        sp1[tid] = beta[m0 + tid] - mean[m0 + tid] * iv;
    }

    f32x4 acc[4][4];
#pragma unroll
    for (int i = 0; i < 4; ++i)
#pragma unroll
        for (int j = 0; j < 4; ++j) acc[i][j] = f32x4{0.f, 0.f, 0.f, 0.f};

    // A: 1024 chunks (256 rows x 4), 2/thread; B: 512 chunks (128 rows x 4), 1/thread
    int ra0 = tid >> 2, ka0 = tid & 3;
    int ra1 = (tid + 512) >> 2, ka1 = tid & 3;
    int wa0 = ra0 * 32 + (ka0 ^ ((ra0 >> 1) & 3)) * 8;
    int wa1 = ra1 * 32 + (ka1 ^ ((ra1 >> 1) & 3)) * 8;
    int rb0 = tid >> 2, kb0 = tid & 3;           // rb0 in [0,128)
    int wb0 = rb0 * 32 + (kb0 ^ ((rb0 >> 1) & 3)) * 8;
    bool doB = (tid < 512);                       // all threads stage B (1 chunk each? 512 chunks)
    // B has 512 chunks and 512 threads: 1 chunk/thread, rb0 = tid>>2 covers 0..127 ✓

    bf16x8 sa0, sa1, sb0;   // reg set 0
    bf16x8 ta0, ta1, tb0;   // reg set 1

    auto LD0 = [&](int kt) {
        const __bf16* Ak = Ab + kt * 32; const __bf16* Bk = Bb + kt * 32;
        sa0 = *(const bf16x8*)(Ak + (size_t)ra0 * CC + ka0 * 8);
        sa1 = *(const bf16x8*)(Ak + (size_t)ra1 * CC + ka1 * 8);
        sb0 = *(const bf16x8*)(Bk + (size_t)rb0 * CC + kb0 * 8);
    };
    auto LD1 = [&](int kt) {
        const __bf16* Ak = Ab + kt * 32; const __bf16* Bk = Bb + kt * 32;
        ta0 = *(const bf16x8*)(Ak + (size_t)ra0 * CC + ka0 * 8);
        ta1 = *(const bf16x8*)(Ak + (size_t)ra1 * CC + ka1 * 8);
        tb0 = *(const bf16x8*)(Bk + (size_t)rb0 * CC + kb0 * 8);
    };
    auto ST0 = [&](int buf) {
        *(bf16x8*)&As[buf][wa0] = sa0; *(bf16x8*)&As[buf][wa1] = sa1;
        *(bf16x8*)&Bs[buf][wb0] = sb0;
    };
    auto ST1 = [&](int buf) {
        *(bf16x8*)&As[buf][wa0] = ta0; *(bf16x8*)&As[buf][wa1] = ta1;
        *(bf16x8*)&Bs[buf][wb0] = tb0;
    };
    auto MMA = [&](int buf) {
        bf16x8 af[4], bg[4];
#pragma unroll
        for (int f = 0; f < 4; ++f) {
            int ra = wm * 64 + f * 16 + (lane & 15);
            af[f] = *(const bf16x8*)&As[buf][ra * 32 + (((lane >> 4) ^ ((ra >> 1) & 3))) * 8];
            int rb = wn * 64 + f * 16 + (lane & 15);
            bg[f] = *(const bf16x8*)&Bs[buf][rb * 32 + (((lane >> 4) ^ ((rb >> 1) & 3))) * 8];
        }
#pragma unroll
        for (int i = 0; i < 4; ++i)
#pragma unroll
            for (int j = 0; j < 4; ++j)
                acc[i][j] = __builtin_amdgcn_mfma_f32_16x16x32_bf16(af[i], bg[j], acc[i][j], 0, 0, 0);
    };

    // prologue: tile0 -> buf0; tile1 loads in flight; Xres prefetch rides along
    LD0(0); ST0(0);
    LD1(1);
    f32x4 xpre[4][4];
#pragma unroll
    for (int mf = 0; mf < 4; ++mf)
#pragma unroll
        for (int nf = 0; nf < 4; ++nf) {
            int o_loc = wn * 64 + nf * 16 + ln;
            int n_loc4 = wm * 64 + mf * 16 + gq * 4;
            xpre[mf][nf] = *(const f32x4*)&Xres[((size_t)b * CC + m0 + o_loc) * NN + n0 + n_loc4];
        }
    __syncthreads();

    for (int kt = 0; kt < 16; kt += 2) {
        if (kt + 2 < 16) LD0(kt + 2);
        MMA(kt % 3);
        ST1((kt + 1) % 3);
        __syncthreads();
        if (kt + 3 < 16) LD1(kt + 3);
        MMA((kt + 1) % 3);
        if (kt + 2 < 16) ST0((kt + 2) % 3);
        __syncthreads();
    }

#pragma unroll
    for (int mf = 0; mf < 4; ++mf) {
#pragma unroll
        for (int nf = 0; nf < 4; ++nf) {
            int o_loc = wn * 64 + nf * 16 + ln;
            int n_loc4 = wm * 64 + mf * 16 + gq * 4;
            size_t addr = ((size_t)b * CC + m0 + o_loc) * NN + n0 + n_loc4;
            float iv = sp0[o_loc], sh = sp1[o_loc];
            f32x4 xi = xpre[mf][nf];
            float4 v;
            v.x = fmaxf(acc[mf][nf][0] * iv + sh + xi[0], 0.f);
            v.y = fmaxf(acc[mf][nf][1] * iv + sh + xi[1], 0.f);
            v.z = fmaxf(acc[mf][nf][2] * iv + sh + xi[2], 0.f);
            v.w = fmaxf(acc[mf][nf][3] * iv + sh + xi[3], 0.f);
            *(float4*)&Out[addr] = v;
        }
    }
}

// ---------------- zsoftmax: logits MFMA + in-register softmax + Z(last)/ZT/zsum ----------------
__global__ __launch_bounds__(256) void k_zsoftmax_mfma(
    const __bf16* __restrict__ XFT, const __bf16* __restrict__ MUT,
    __bf16* __restrict__ Z, __bf16* __restrict__ ZT, float* __restrict__ ZSUM,
    int write_z) {
    __shared__ __bf16 As[2][128 * 32];
    __shared__ __bf16 Bs[2][64 * 32];
    __shared__ __bf16 ZL[64][136];     // [k][n] tile for coalesced writeouts
    int tid = threadIdx.x;
    int lane = tid & 63, wave = tid >> 6;
    int n0 = blockIdx.x * 128, b = blockIdx.y;
    const __bf16* Ab = XFT + ((size_t)b * NN + n0) * CC;
    const __bf16* Bb = MUT + (size_t)b * KK * CC;

    f32x4 acc[2][4];
#pragma unroll
    for (int i = 0; i < 2; ++i)
#pragma unroll
        for (int j = 0; j < 4; ++j) acc[i][j] = f32x4{0.f, 0.f, 0.f, 0.f};

    int r0 = tid >> 2, k0c = tid & 3;
    int r1 = (tid + 256) >> 2, k1c = tid & 3;
    int w0 = r0 * 32 + (k0c ^ ((r0 >> 1) & 3)) * 8;
    int w1 = r1 * 32 + (k1c ^ ((r1 >> 1) & 3)) * 8;
    int rB = tid >> 2, kB = tid & 3;
    int wB = rB * 32 + (kB ^ ((rB >> 1) & 3)) * 8;

    bf16x8 va0, va1, vb0;
    va0 = *(const bf16x8*)(Ab + (size_t)r0 * CC + k0c * 8);
    va1 = *(const bf16x8*)(Ab + (size_t)r1 * CC + k1c * 8);
    vb0 = *(const bf16x8*)(Bb + (size_t)rB * CC + kB * 8);
    *(bf16x8*)&As[0][w0] = va0; *(bf16x8*)&As[0][w1] = va1;
    *(bf16x8*)&Bs[0][wB] = vb0;
    __syncthreads();

    for (int kt = 0; kt < 16; ++kt) {
        int s = kt & 1;
        if (kt < 15) {
            const __bf16* Ak = Ab + (kt + 1) * 32;
            const __bf16* Bk = Bb + (kt + 1) * 32;
            va0 = *(const bf16x8*)(Ak + (size_t)r0 * CC + k0c * 8);
            va1 = *(const bf16x8*)(Ak + (size_t)r1 * CC + k1c * 8);
            vb0 = *(const bf16x8*)(Bk + (size_t)rB * CC + kB * 8);
        }
        bf16x8 af[2], bg[4];
#pragma unroll
        for (int f = 0; f < 2; ++f) {
            int ra = wave * 32 + f * 16 + (lane & 15);
            af[f] = *(const bf16x8*)&As[s][ra * 32 + (((lane >> 4) ^ ((ra >> 1) & 3))) * 8];
        }
#pragma unroll
        for (int f = 0; f < 4; ++f) {
            int rb = f * 16 + (lane & 15);
            bg[f] = *(const bf16x8*)&Bs[s][rb * 32 + (((lane >> 4) ^ ((rb >> 1) & 3))) * 8];
        }
#pragma unroll
        for (int i = 0; i < 2; ++i)
#pragma unroll
            for (int j = 0; j < 4; ++j)
                acc[i][j] = __builtin_amdgcn_mfma_f32_16x16x32_bf16(af[i], bg[j], acc[i][j], 0, 0, 0);
        if (kt < 15) {
            *(bf16x8*)&As[s ^ 1][w0] = va0; *(bf16x8*)&As[s ^ 1][w1] = va1;
            *(bf16x8*)&Bs[s ^ 1][wB] = vb0;
        }
        __syncthreads();
    }

    // softmax over k=64 per row; each row owned by 16 lanes (same lane>>4 group)
    int gq = lane >> 4, ln = lane & 15;
    float zp[4] = {0.f, 0.f, 0.f, 0.f};
#pragma unroll
    for (int mf = 0; mf < 2; ++mf) {
#pragma unroll
        for (int r = 0; r < 4; ++r) {
            float mx = fmaxf(fmaxf(acc[mf][0][r], acc[mf][1][r]),
                             fmaxf(acc[mf][2][r], acc[mf][3][r]));
            mx = fmaxf(mx, __shfl_xor(mx, 1));
            mx = fmaxf(mx, __shfl_xor(mx, 2));
            mx = fmaxf(mx, __shfl_xor(mx, 4));
            mx = fmaxf(mx, __shfl_xor(mx, 8));
            float e[4];
            float ssum = 0.f;
#pragma unroll
            for (int nf = 0; nf < 4; ++nf) { e[nf] = expf(acc[mf][nf][r] - mx); ssum += e[nf]; }
            ssum += __shfl_xor(ssum, 1);
            ssum += __shfl_xor(ssum, 2);
            ssum += __shfl_xor(ssum, 4);
            ssum += __shfl_xor(ssum, 8);
            float inv = 1.0f / ssum;
            int n_loc = wave * 32 + mf * 16 + gq * 4 + r;
#pragma unroll
            for (int nf = 0; nf < 4; ++nf) {
                float zv = e[nf] * inv;
                zp[nf] += zv;
                ZL[nf * 16 + ln][n_loc] = (__bf16)zv;
            }
        }
    }
#pragma unroll
    for (int nf = 0; nf < 4; ++nf) {
        float t = zp[nf];
        t += __shfl_xor(t, 16);
        t += __shfl_xor(t, 32);
        if (lane < 16) atomicAdd(&ZSUM[b * KK + nf * 16 + ln], t);
    }
    __syncthreads();
    // coalesced ZT writeout: 64 k-rows x 128 n, bf16x8 chunks
#pragma unroll
    for (int p = 0; p < 4; ++p) {
        int ci = tid + p * 256;
        int kr = ci >> 4, ch = (ci & 15) * 8;
        bf16x8 v = *(const bf16x8*)&ZL[kr][ch];
        *(bf16x8*)&ZT[((size_t)b * KK + kr) * NN + n0 + ch] = v;
    }
    // Z[n][k] writeout only when consumed (last EM iteration)
    if (write_z) {
#pragma unroll
        for (int p = 0; p < 4; ++p) {
            int idx = tid + p * 256;
            int row = idx >> 3, k8 = (idx & 7) * 8;
            bf16x8 o;
#pragma unroll
            for (int j = 0; j < 8; ++j) o[j] = ZL[k8 + j][row];
            *(bf16x8*)&Z[((size_t)b * NN + n0 + row) * KK + k8] = o;
        }
    }
}

// ---------------- muacc: MUACC[c][k] += sum_n XFC[c][n]·ZT[k][n], split-K over n ----------------
__global__ __launch_bounds__(256) void k_muacc_mfma(
    const __bf16* __restrict__ XFC, const __bf16* __restrict__ ZT,
    float* __restrict__ MUACC) {
    __shared__ __bf16 As[2][128 * 32];
    __shared__ __bf16 Bs[2][64 * 32];
    int tid = threadIdx.x;
    int lane = tid & 63, wave = tid >> 6;
    int wm = wave >> 1, wn = wave & 1;
    int c0 = (blockIdx.x & 3) * 128, sp = blockIdx.x >> 2, b = blockIdx.y;
    size_t nbase = (size_t)sp * 512;
    const __bf16* Ab = XFC + ((size_t)b * CC + c0) * NN + nbase;
    const __bf16* Bb = ZT + (size_t)b * KK * NN + nbase;

    f32x4 acc[4][2];
#pragma unroll
    for (int i = 0; i < 4; ++i)
#pragma unroll
        for (int j = 0; j < 2; ++j) acc[i][j] = f32x4{0.f, 0.f, 0.f, 0.f};

    int r0 = tid >> 2, k0c = tid & 3;
    int r1 = (tid + 256) >> 2, k1c = tid & 3;
    int w0 = r0 * 32 + (k0c ^ ((r0 >> 1) & 3)) * 8;
    int w1 = r1 * 32 + (k1c ^ ((r1 >> 1) & 3)) * 8;
    int rB = tid >> 2, kB = tid & 3;
    int wB = rB * 32 + (kB ^ ((rB >> 1) & 3)) * 8;

    bf16x8 va0, va1, vb0;
    va0 = *(const bf16x8*)(Ab + (size_t)r0 * NN + k0c * 8);
    va1 = *(const bf16x8*)(Ab + (size_t)r1 * NN + k1c * 8);
    vb0 = *(const bf16x8*)(Bb + (size_t)rB * NN + kB * 8);
    *(bf16x8*)&As[0][w0] = va0; *(bf16x8*)&As[0][w1] = va1;
    *(bf16x8*)&Bs[0][wB] = vb0;
    __syncthreads();

    for (int kt = 0; kt < 16; ++kt) {
        int s = kt & 1;
        if (kt < 15) {
            const __bf16* Ak = Ab + (kt + 1) * 32;
            const __bf16* Bk = Bb + (kt + 1) * 32;
            va0 = *(const bf16x8*)(Ak + (size_t)r0 * NN + k0c * 8);
            va1 = *(const bf16x8*)(Ak + (size_t)r1 * NN + k1c * 8);
            vb0 = *(const bf16x8*)(Bk + (size_t)rB * NN + kB * 8);
        }
        bf16x8 af[4], bg[2];
#pragma unroll
        for (int f = 0; f < 4; ++f) {
            int ra = wm * 64 + f * 16 + (lane & 15);
            af[f] = *(const bf16x8*)&As[s][ra * 32 + (((lane >> 4) ^ ((ra >> 1) & 3))) * 8];
        }
#pragma unroll
        for (int f = 0; f < 2; ++f) {
            int rb = wn * 32 + f * 16 + (lane & 15);
            bg[f] = *(const bf16x8*)&Bs[s][rb * 32 + (((lane >> 4) ^ ((rb >> 1) & 3))) * 8];
        }
#pragma unroll
        for (int i = 0; i < 4; ++i)
#pragma unroll
            for (int j = 0; j < 2; ++j)
                acc[i][j] = __builtin_amdgcn_mfma_f32_16x16x32_bf16(af[i], bg[j], acc[i][j], 0, 0, 0);
        if (kt < 15) {
            *(bf16x8*)&As[s ^ 1][w0] = va0; *(bf16x8*)&As[s ^ 1][w1] = va1;
            *(bf16x8*)&Bs[s ^ 1][wB] = vb0;
        }
        __syncthreads();
    }

    int gq = lane >> 4, ln = lane & 15;
#pragma unroll
    for (int mf = 0; mf < 4; ++mf) {
#pragma unroll
        for (int r = 0; r < 4; ++r) {
            int row = wm * 64 + mf * 16 + gq * 4 + r;
#pragma unroll
            for (int nf = 0; nf < 2; ++nf) {
                int col = wn * 32 + nf * 16 + ln;
                atomicAdd(&MUACC[((size_t)b * CC + c0 + row) * KK + col], acc[mf][nf][r]);
            }
        }
    }
}

// ---------------- munorm -> bf16 mu (both layouts); re-zeroes MUACC/ZSUM for next iter ----------------
__global__ __launch_bounds__(64) void k_munorm_bf(
    float* __restrict__ MUACC, float* __restrict__ ZSUM,
    __bf16* __restrict__ mu_bf, __bf16* __restrict__ muT_bf) {
    int k = blockIdx.x;
    int b = blockIdx.y;
    int lane = threadIdx.x;
    float scale = 1.0f / (1e-6f + ZSUM[b * KK + k]);
    float v[8];
    float ss = 0.f;
#pragma unroll
    for (int i = 0; i < 8; ++i) {
        size_t a = (size_t)b * CC * KK + (size_t)(lane + i * 64) * KK + k;
        v[i] = MUACC[a] * scale;
        MUACC[a] = 0.f;               // re-zero for the next EM iteration
        ss += v[i] * v[i];
    }
    if (lane == 0) ZSUM[b * KK + k] = 0.f;
    for (int off = 32; off; off >>= 1) ss += __shfl_xor(ss, off);
    float nrm = 1.0f / (1e-6f + sqrtf(ss));
#pragma unroll
    for (int i = 0; i < 8; ++i) {
        int c = lane + i * 64;
        __bf16 o = (__bf16)(v[i] * nrm);
        mu_bf[((size_t)b * CC + c) * KK + k] = o;
        muT_bf[((size_t)b * KK + k) * CC + c] = o;
    }
}

// ---------------- xr: XRT[b][n][c] = bf16(relu( sum_k Z[n][k]·mu[c][k] )), K=64 ----------------
__global__ __launch_bounds__(256) void k_xr_mfma(
    const __bf16* __restrict__ Zm, const __bf16* __restrict__ MUB,
    __bf16* __restrict__ XRT) {
    __shared__ __bf16 SM[17408];    // As(8192)+Bs(8192); aliased by TT[128][136]
    __bf16* As = SM;
    __bf16* Bs = SM + 8192;
    int tid = threadIdx.x;
    int lane = tid & 63, wave = tid >> 6;
    int wm = wave >> 1, wn = wave & 1;
    int n0 = blockIdx.x * 128, c0 = blockIdx.y * 128, b = blockIdx.z;
    const __bf16* Ab = Zm + ((size_t)b * NN + n0) * KK;
    const __bf16* Bb = MUB + ((size_t)b * CC + c0) * KK;
#pragma unroll
    for (int p = 0; p < 4; ++p) {
        int idx = tid + p * 256;
        int r = idx >> 3, ch = idx & 7;
        int woff = r * 64 + ((ch ^ (r & 7)) * 8);
        *(bf16x8*)&As[woff] = *(const bf16x8*)(Ab + (size_t)r * KK + ch * 8);
        *(bf16x8*)&Bs[woff] = *(const bf16x8*)(Bb + (size_t)r * KK + ch * 8);
    }
    __syncthreads();

    f32x4 acc[4][4];
#pragma unroll
    for (int i = 0; i < 4; ++i)
#pragma unroll
        for (int j = 0; j < 4; ++j) acc[i][j] = f32x4{0.f, 0.f, 0.f, 0.f};

    int gq = lane >> 4, ln = lane & 15;
#pragma unroll
    for (int ks = 0; ks < 2; ++ks) {
        bf16x8 af[4], bg[4];
#pragma unroll
        for (int f = 0; f < 4; ++f) {
            int ra = wm * 64 + f * 16 + ln;
            af[f] = *(const bf16x8*)&As[ra * 64 + (((ks * 4 + gq) ^ (ra & 7))) * 8];
            int rb = wn * 64 + f * 16 + ln;
            bg[f] = *(const bf16x8*)&Bs[rb * 64 + (((ks * 4 + gq) ^ (rb & 7))) * 8];
        }
#pragma unroll
        for (int i = 0; i < 4; ++i)
#pragma unroll
            for (int j = 0; j < 4; ++j)
                acc[i][j] = __builtin_amdgcn_mfma_f32_16x16x32_bf16(af[i], bg[j], acc[i][j], 0, 0, 0);
    }
    __syncthreads();   // all As/Bs reads done before TT alias writes

    __bf16* TT = SM;   // TT[128n][136]
#pragma unroll
    for (int mf = 0; mf < 4; ++mf) {
#pragma unroll
        for (int nf = 0; nf < 4; ++nf) {
            int c_loc = wn * 64 + nf * 16 + ln;
            int n_loc4 = wm * 64 + mf * 16 + gq * 4;
#pragma unroll
            for (int r = 0; r < 4; ++r)
                TT[(n_loc4 + r) * 136 + c_loc] = (__bf16)fmaxf(acc[mf][nf][r], 0.f);
        }
    }
    __syncthreads();
#pragma unroll
    for (int p = 0; p < 8; ++p) {
        int idx = tid + p * 256;
        int row = idx >> 4, ch = idx & 15;
        bf16x8 v = *(const bf16x8*)&TT[row * 136 + ch * 8];
        *(bf16x8*)&XRT[((size_t)b * NN + n0 + row) * CC + c0 + ch * 8] = v;
    }
}

extern "C" void kernel_launch(void* const* d_in, const int* in_sizes, int n_in,
                              void* d_out, int out_size, void* d_ws, size_t ws_size,
                              hipStream_t stream) {
    const float* x     = (const float*)d_in[0];
    const float* w1    = (const float*)d_in[1];
    const float* b1    = (const float*)d_in[2];
    const float* mu_in = (const float*)d_in[3];
    const float* w2    = (const float*)d_in[4];
    const float* gamma = (const float*)d_in[5];
    const float* beta  = (const float*)d_in[6];
    const float* mean  = (const float*)d_in[7];
    const float* var   = (const float*)d_in[8];
    float* out = (float*)d_out;
    float* ws  = (float*)d_ws;

    __bf16* xt    = (__bf16*)(ws + R1_OFF);
    __bf16* xft   = (__bf16*)(ws + R2_OFF);    // region 2: XFT, later XRT
    __bf16* xrt   = (__bf16*)(ws + R2_OFF);
    __bf16* xfc   = (__bf16*)d_out;            // XFC staged in d_out (dead until conv2 writes)
    __bf16* zbf   = (__bf16*)(ws + Z_OFF);
    __bf16* ztbf  = (__bf16*)(ws + ZT_OFF);
    float*  muacc = ws + MUACC_OFF;
    float*  zsum  = ws + ZSUM_OFF;
    __bf16* mu_bf = (__bf16*)(ws + MUBF_OFF);
    __bf16* muT_bf= (__bf16*)(ws + MUTBF_OFF);
    __bf16* w1bf  = (__bf16*)(ws + W1BF_OFF);
    __bf16* w2bf  = (__bf16*)(ws + W2BF_OFF);

    // one memset covers MUACC+ZSUM (contiguous); k_munorm_bf re-zeroes them each iter
    hipMemsetAsync(muacc, 0, (size_t)(BB * CC * KK + BB * KK) * sizeof(float), stream);
    hipLaunchKernelGGL(k_cvt2, dim3(256), dim3(256), 0, stream, w1, w2, w1bf, w2bf);
    hipLaunchKernelGGL(k_mu_bcast_bf, dim3(128), dim3(256), 0, stream, mu_in, mu_bf, muT_bf);
    hipLaunchKernelGGL(k_xpose_cvt, dim3(NN / 64, CC / 64, BB), dim3(256), 0, stream, x, xt);
    hipLaunchKernelGGL(k_conv1_mfma, dim3(CC / 128, NN / 128, BB), dim3(256), 0, stream,
                       xt, w1bf, b1, xft, xfc);
    for (int it = 0; it < 3; ++it) {
        hipLaunchKernelGGL(k_zsoftmax_mfma, dim3(NN / 128, BB), dim3(256), 0, stream,
                           xft, muT_bf, zbf, ztbf, zsum, (it == 2) ? 1 : 0);
        hipLaunchKernelGGL(k_muacc_mfma, dim3(32, BB), dim3(256), 0, stream, xfc, ztbf, muacc);
        hipLaunchKernelGGL(k_munorm_bf, dim3(KK, BB), dim3(64), 0, stream, muacc, zsum,
                           mu_bf, muT_bf);
    }
    hipLaunchKernelGGL(k_xr_mfma, dim3(NN / 128, CC / 128, BB), dim3(256), 0, stream,
                       zbf, mu_bf, xrt);
    // conv2: 256x128 tile, 512 threads/block
    hipLaunchKernelGGL(k_conv2_mfma, dim3(NN / 256, CC / 128, BB), dim3(512), 0, stream,
                       w2bf, xrt, gamma, beta, mean, var, x, out);
}

// Round 17
// 428.686 us; speedup vs baseline: 1.0084x; 1.0084x over previous
//
#include <hip/hip_runtime.h>

typedef __bf16 bf16x8 __attribute__((ext_vector_type(8)));
typedef __bf16 bf16x4 __attribute__((ext_vector_type(4)));
typedef float f32x4 __attribute__((ext_vector_type(4)));

constexpr int CC = 512;   // channels
constexpr int KK = 64;    // bases
constexpr int NN = 4096;  // h*w
constexpr int BB = 16;    // batch

// workspace layout (float units)
constexpr size_t R1_OFF    = 0;                     // XT bf16 [b][n][c]
constexpr size_t R2_OFF    = 16777216;              // XFT bf16 [b][n][c], later XRT bf16 [b][n][c]
constexpr size_t Z_OFF     = 33554432;              // Z  bf16 [b][n][k]
constexpr size_t ZT_OFF    = 35651584;              // ZT bf16 [b][k][n]
constexpr size_t MUACC_OFF = 37748736;              // fp32 [b][c][k]
constexpr size_t ZSUM_OFF  = 38273024;              // fp32 [b][k]
constexpr size_t MUBF_OFF  = 38274048;              // bf16 [b][c][k]
constexpr size_t MUTBF_OFF = 38536192;              // bf16 [b][k][c]
constexpr size_t W1BF_OFF  = 38798336;              // bf16 [o][c]
constexpr size_t W2BF_OFF  = 38929408;              // bf16 [o][c]
// XFC bf16 [b][c][n] lives in d_out (dead until conv2 writes the final output)

// ---------------- fp32 -> bf16 convert, both weight matrices in one launch ----------------
__global__ __launch_bounds__(256) void k_cvt2(const float* __restrict__ w1,
                                              const float* __restrict__ w2,
                                              __bf16* __restrict__ d1,
                                              __bf16* __restrict__ d2) {
    int blk = blockIdx.x;
    const float* src = (blk < 128) ? w1 : w2;
    __bf16* dst = (blk < 128) ? d1 : d2;
    int i = (blk & 127) * 256 + threadIdx.x;
    const float4* s4 = (const float4*)src;
    float4 a = s4[i * 2], b = s4[i * 2 + 1];
    bf16x8 o;
    o[0] = (__bf16)a.x; o[1] = (__bf16)a.y; o[2] = (__bf16)a.z; o[3] = (__bf16)a.w;
    o[4] = (__bf16)b.x; o[5] = (__bf16)b.y; o[6] = (__bf16)b.z; o[7] = (__bf16)b.w;
    *(bf16x8*)&dst[(size_t)i * 8] = o;
}

// ---------------- initial mu broadcast to both bf16 layouts ----------------
__global__ __launch_bounds__(256) void k_mu_bcast_bf(const float* __restrict__ mu_in,
                                                     __bf16* __restrict__ mu_bf,
                                                     __bf16* __restrict__ muT_bf) {
    int idx = blockIdx.x * 256 + threadIdx.x;
    if (idx < CC * KK) {
        int c = idx >> 6, k = idx & 63;
        __bf16 v = (__bf16)mu_in[idx];
        for (int b = 0; b < BB; ++b) {
            mu_bf[(size_t)b * CC * KK + idx] = v;
            muT_bf[((size_t)b * KK + k) * CC + c] = v;
        }
    }
}

// ---------------- X [b][c][n] fp32 -> XT [b][n][c] bf16 ----------------
__global__ __launch_bounds__(256) void k_xpose_cvt(const float* __restrict__ X,
                                                   __bf16* __restrict__ XT) {
    int n0 = blockIdx.x * 64, c0 = blockIdx.y * 64, b = blockIdx.z;
    __shared__ float T[64][65];
    int tid = threadIdx.x;
    const float* Xb = X + (size_t)b * CC * NN;
#pragma unroll
    for (int p = 0; p < 4; ++p) {
        int f4 = tid + p * 256;
        int row = f4 >> 4, col4 = (f4 & 15) * 4;
        float4 v = *(const float4*)&Xb[(size_t)(c0 + row) * NN + n0 + col4];
        T[row][col4 + 0] = v.x; T[row][col4 + 1] = v.y;
        T[row][col4 + 2] = v.z; T[row][col4 + 3] = v.w;
    }
    __syncthreads();
#pragma unroll
    for (int p = 0; p < 2; ++p) {
        int q = tid + p * 256;
        int nl = q >> 3, c8 = (q & 7) * 8;
        bf16x8 o;
#pragma unroll
        for (int j = 0; j < 8; ++j) o[j] = (__bf16)T[c8 + j][nl];
        *(bf16x8*)&XT[((size_t)b * NN + n0 + nl) * CC + c0 + c8] = o;
    }
}

// ---------------- conv1: 2-deep prefetch, 3-buffer LDS; XFT + XFC outputs ----------------
__global__ __launch_bounds__(256) void k_conv1_mfma(
    const __bf16* __restrict__ XT, const __bf16* __restrict__ W1,
    const float* __restrict__ bias, __bf16* __restrict__ XFT,
    __bf16* __restrict__ XFC) {
    __shared__ __bf16 SM[24576];     // As(3x4096) + Bs(3x4096); TT[128][136] aliases (17408 elems)
    __shared__ float sbias[128];
    __bf16* As = SM;                 // As[buf*4096 + w]
    __bf16* Bs = SM + 12288;
    int tid = threadIdx.x;
    int lane = tid & 63, wave = tid >> 6;
    int wm = wave >> 1, wn = wave & 1;
    int o0 = blockIdx.x * 128, n0 = blockIdx.y * 128, b = blockIdx.z;
    const __bf16* Ab = XT + ((size_t)b * NN + n0) * CC;
    const __bf16* Bb = W1 + (size_t)o0 * CC;
    if (tid < 128) sbias[tid] = bias[o0 + tid];

    f32x4 acc[4][4];
#pragma unroll
    for (int i = 0; i < 4; ++i)
#pragma unroll
        for (int j = 0; j < 4; ++j) acc[i][j] = f32x4{0.f, 0.f, 0.f, 0.f};

    int r0 = tid >> 2, k0c = tid & 3;
    int r1 = (tid + 256) >> 2, k1c = tid & 3;
    int w0 = r0 * 32 + (k0c ^ ((r0 >> 1) & 3)) * 8;
    int w1 = r1 * 32 + (k1c ^ ((r1 >> 1) & 3)) * 8;

    bf16x8 sa0, sa1, sb0, sb1;   // reg set 0
    bf16x8 ta0, ta1, tb0, tb1;   // reg set 1

    auto LD0 = [&](int kt) {
        const __bf16* Ak = Ab + kt * 32; const __bf16* Bk = Bb + kt * 32;
        sa0 = *(const bf16x8*)(Ak + (size_t)r0 * CC + k0c * 8);
        sa1 = *(const bf16x8*)(Ak + (size_t)r1 * CC + k1c * 8);
        sb0 = *(const bf16x8*)(Bk + (size_t)r0 * CC + k0c * 8);
        sb1 = *(const bf16x8*)(Bk + (size_t)r1 * CC + k1c * 8);
    };
    auto LD1 = [&](int kt) {
        const __bf16* Ak = Ab + kt * 32; const __bf16* Bk = Bb + kt * 32;
        ta0 = *(const bf16x8*)(Ak + (size_t)r0 * CC + k0c * 8);
        ta1 = *(const bf16x8*)(Ak + (size_t)r1 * CC + k1c * 8);
        tb0 = *(const bf16x8*)(Bk + (size_t)r0 * CC + k0c * 8);
        tb1 = *(const bf16x8*)(Bk + (size_t)r1 * CC + k1c * 8);
    };
    auto ST0 = [&](int buf) {
        *(bf16x8*)&As[buf * 4096 + w0] = sa0; *(bf16x8*)&As[buf * 4096 + w1] = sa1;
        *(bf16x8*)&Bs[buf * 4096 + w0] = sb0; *(bf16x8*)&Bs[buf * 4096 + w1] = sb1;
    };
    auto ST1 = [&](int buf) {
        *(bf16x8*)&As[buf * 4096 + w0] = ta0; *(bf16x8*)&As[buf * 4096 + w1] = ta1;
        *(bf16x8*)&Bs[buf * 4096 + w0] = tb0; *(bf16x8*)&Bs[buf * 4096 + w1] = tb1;
    };
    auto MMA = [&](int buf) {
        bf16x8 af[4], bg[4];
#pragma unroll
        for (int f = 0; f < 4; ++f) {
            int ra = wm * 64 + f * 16 + (lane & 15);
            af[f] = *(const bf16x8*)&As[buf * 4096 + ra * 32 + (((lane >> 4) ^ ((ra >> 1) & 3))) * 8];
            int rb = wn * 64 + f * 16 + (lane & 15);
            bg[f] = *(const bf16x8*)&Bs[buf * 4096 + rb * 32 + (((lane >> 4) ^ ((rb >> 1) & 3))) * 8];
        }
#pragma unroll
        for (int i = 0; i < 4; ++i)
#pragma unroll
            for (int j = 0; j < 4; ++j)
                acc[i][j] = __builtin_amdgcn_mfma_f32_16x16x32_bf16(af[i], bg[j], acc[i][j], 0, 0, 0);
    };

    // prologue: tile0 -> buf0; tile1 loads in flight (set1)
    LD0(0); ST0(0);
    LD1(1);
    __syncthreads();

    for (int kt = 0; kt < 16; kt += 2) {
        if (kt + 2 < 16) LD0(kt + 2);
        MMA(kt % 3);
        ST1((kt + 1) % 3);
        __syncthreads();
        if (kt + 3 < 16) LD1(kt + 3);
        MMA((kt + 1) % 3);
        if (kt + 2 < 16) ST0((kt + 2) % 3);
        __syncthreads();
    }

    // epilogue: XFC vectorized direct; XFT via LDS transpose tile TT[128n][136]
    __bf16* TT = SM;
    int gq = lane >> 4, ln = lane & 15;
#pragma unroll
    for (int mf = 0; mf < 4; ++mf) {
#pragma unroll
        for (int nf = 0; nf < 4; ++nf) {
            int o_loc = wn * 64 + nf * 16 + ln;
            int n_loc4 = wm * 64 + mf * 16 + gq * 4;
            float bi = sbias[o_loc];
            bf16x4 oc;
#pragma unroll
            for (int r = 0; r < 4; ++r) oc[r] = (__bf16)(acc[mf][nf][r] + bi);
            *(bf16x4*)&XFC[((size_t)b * CC + o0 + o_loc) * NN + n0 + n_loc4] = oc;
#pragma unroll
            for (int r = 0; r < 4; ++r) TT[(n_loc4 + r) * 136 + o_loc] = oc[r];
        }
    }
    __syncthreads();
#pragma unroll
    for (int p = 0; p < 8; ++p) {
        int idx = tid + p * 256;
        int row = idx >> 4, ch = idx & 15;
        bf16x8 v = *(const bf16x8*)&TT[row * 136 + ch * 8];
        *(bf16x8*)&XFT[((size_t)b * NN + n0 + row) * CC + o0 + ch * 8] = v;
    }
}

// ---------------- conv2: 2-deep prefetch, 3-buffer LDS; Xres reg-prefetch epilogue ----------------
__global__ __launch_bounds__(256) void k_conv2_mfma(
    const __bf16* __restrict__ W2, const __bf16* __restrict__ XRT,
    const float* __restrict__ gamma, const float* __restrict__ beta,
    const float* __restrict__ mean, const float* __restrict__ var,
    const float* __restrict__ Xres, float* __restrict__ Out) {
    __shared__ __bf16 As[3][4096];   // XRT rows (n)
    __shared__ __bf16 Bs[3][4096];   // W2 rows (o)
    __shared__ float sp0[128], sp1[128];
    int tid = threadIdx.x;
    int lane = tid & 63, wave = tid >> 6;
    int wm = wave >> 1, wn = wave & 1;
    int n0 = blockIdx.x * 128, m0 = blockIdx.y * 128, b = blockIdx.z;
    const __bf16* Ab = XRT + ((size_t)b * NN + n0) * CC;
    const __bf16* Bb = W2 + (size_t)m0 * CC;
    int gq = lane >> 4, ln = lane & 15;
    if (tid < 128) {
        float iv = gamma[m0 + tid] * rsqrtf(var[m0 + tid] + 1e-5f);
        sp0[tid] = iv;
        sp1[tid] = beta[m0 + tid] - mean[m0 + tid] * iv;
    }

    f32x4 acc[4][4];
#pragma unroll
    for (int i = 0; i < 4; ++i)
#pragma unroll
        for (int j = 0; j < 4; ++j) acc[i][j] = f32x4{0.f, 0.f, 0.f, 0.f};

    int r0 = tid >> 2, k0c = tid & 3;
    int r1 = (tid + 256) >> 2, k1c = tid & 3;
    int w0 = r0 * 32 + (k0c ^ ((r0 >> 1) & 3)) * 8;
    int w1 = r1 * 32 + (k1c ^ ((r1 >> 1) & 3)) * 8;

    bf16x8 sa0, sa1, sb0, sb1;   // reg set 0
    bf16x8 ta0, ta1, tb0, tb1;   // reg set 1

    auto LD0 = [&](int kt) {
        const __bf16* Ak = Ab + kt * 32; const __bf16* Bk = Bb + kt * 32;
        sa0 = *(const bf16x8*)(Ak + (size_t)r0 * CC + k0c * 8);
        sa1 = *(const bf16x8*)(Ak + (size_t)r1 * CC + k1c * 8);
        sb0 = *(const bf16x8*)(Bk + (size_t)r0 * CC + k0c * 8);
        sb1 = *(const bf16x8*)(Bk + (size_t)r1 * CC + k1c * 8);
    };
    auto LD1 = [&](int kt) {
        const __bf16* Ak = Ab + kt * 32; const __bf16* Bk = Bb + kt * 32;
        ta0 = *(const bf16x8*)(Ak + (size_t)r0 * CC + k0c * 8);
        ta1 = *(const bf16x8*)(Ak + (size_t)r1 * CC + k1c * 8);
        tb0 = *(const bf16x8*)(Bk + (size_t)r0 * CC + k0c * 8);
        tb1 = *(const bf16x8*)(Bk + (size_t)r1 * CC + k1c * 8);
    };
    auto ST0 = [&](int buf) {
        *(bf16x8*)&As[buf][w0] = sa0; *(bf16x8*)&As[buf][w1] = sa1;
        *(bf16x8*)&Bs[buf][w0] = sb0; *(bf16x8*)&Bs[buf][w1] = sb1;
    };
    auto ST1 = [&](int buf) {
        *(bf16x8*)&As[buf][w0] = ta0; *(bf16x8*)&As[buf][w1] = ta1;
        *(bf16x8*)&Bs[buf][w0] = tb0; *(bf16x8*)&Bs[buf][w1] = tb1;
    };
    auto MMA = [&](int buf) {
        bf16x8 af[4], bg[4];
#pragma unroll
        for (int f = 0; f < 4; ++f) {
            int ra = wm * 64 + f * 16 + (lane & 15);
            af[f] = *(const bf16x8*)&As[buf][ra * 32 + (((lane >> 4) ^ ((ra >> 1) & 3))) * 8];
            int rb = wn * 64 + f * 16 + (lane & 15);
            bg[f] = *(const bf16x8*)&Bs[buf][rb * 32 + (((lane >> 4) ^ ((rb >> 1) & 3))) * 8];
        }
#pragma unroll
        for (int i = 0; i < 4; ++i)
#pragma unroll
            for (int j = 0; j < 4; ++j)
                acc[i][j] = __builtin_amdgcn_mfma_f32_16x16x32_bf16(af[i], bg[j], acc[i][j], 0, 0, 0);
    };

    // prologue: tile0 -> buf0; tile1 loads in flight; Xres prefetch rides along
    LD0(0); ST0(0);
    LD1(1);
    f32x4 xpre[4][4];
#pragma unroll
    for (int mf = 0; mf < 4; ++mf)
#pragma unroll
        for (int nf = 0; nf < 4; ++nf) {
            int o_loc = wn * 64 + nf * 16 + ln;
            int n_loc4 = wm * 64 + mf * 16 + gq * 4;
            xpre[mf][nf] = *(const f32x4*)&Xres[((size_t)b * CC + m0 + o_loc) * NN + n0 + n_loc4];
        }
    __syncthreads();

    for (int kt = 0; kt < 16; kt += 2) {
        if (kt + 2 < 16) LD0(kt + 2);
        MMA(kt % 3);
        ST1((kt + 1) % 3);
        __syncthreads();
        if (kt + 3 < 16) LD1(kt + 3);
        MMA((kt + 1) % 3);
        if (kt + 2 < 16) ST0((kt + 2) % 3);
        __syncthreads();
    }

#pragma unroll
    for (int mf = 0; mf < 4; ++mf) {
#pragma unroll
        for (int nf = 0; nf < 4; ++nf) {
            int o_loc = wn * 64 + nf * 16 + ln;
            int n_loc4 = wm * 64 + mf * 16 + gq * 4;
            size_t addr = ((size_t)b * CC + m0 + o_loc) * NN + n0 + n_loc4;
            float iv = sp0[o_loc], sh = sp1[o_loc];
            f32x4 xi = xpre[mf][nf];
            float4 v;
            v.x = fmaxf(acc[mf][nf][0] * iv + sh + xi[0], 0.f);
            v.y = fmaxf(acc[mf][nf][1] * iv + sh + xi[1], 0.f);
            v.z = fmaxf(acc[mf][nf][2] * iv + sh + xi[2], 0.f);
            v.w = fmaxf(acc[mf][nf][3] * iv + sh + xi[3], 0.f);
            *(float4*)&Out[addr] = v;
        }
    }
}

// ---------------- zsoftmax: logits MFMA + in-register softmax + Z(last)/ZT/zsum ----------------
__global__ __launch_bounds__(256) void k_zsoftmax_mfma(
    const __bf16* __restrict__ XFT, const __bf16* __restrict__ MUT,
    __bf16* __restrict__ Z, __bf16* __restrict__ ZT, float* __restrict__ ZSUM,
    int write_z) {
    __shared__ __bf16 As[2][128 * 32];
    __shared__ __bf16 Bs[2][64 * 32];
    __shared__ __bf16 ZL[64][136];     // [k][n] tile for coalesced writeouts
    int tid = threadIdx.x;
    int lane = tid & 63, wave = tid >> 6;
    int n0 = blockIdx.x * 128, b = blockIdx.y;
    const __bf16* Ab = XFT + ((size_t)b * NN + n0) * CC;
    const __bf16* Bb = MUT + (size_t)b * KK * CC;

    f32x4 acc[2][4];
#pragma unroll
    for (int i = 0; i < 2; ++i)
#pragma unroll
        for (int j = 0; j < 4; ++j) acc[i][j] = f32x4{0.f, 0.f, 0.f, 0.f};

    int r0 = tid >> 2, k0c = tid & 3;
    int r1 = (tid + 256) >> 2, k1c = tid & 3;
    int w0 = r0 * 32 + (k0c ^ ((r0 >> 1) & 3)) * 8;
    int w1 = r1 * 32 + (k1c ^ ((r1 >> 1) & 3)) * 8;
    int rB = tid >> 2, kB = tid & 3;
    int wB = rB * 32 + (kB ^ ((rB >> 1) & 3)) * 8;

    bf16x8 va0, va1, vb0;
    va0 = *(const bf16x8*)(Ab + (size_t)r0 * CC + k0c * 8);
    va1 = *(const bf16x8*)(Ab + (size_t)r1 * CC + k1c * 8);
    vb0 = *(const bf16x8*)(Bb + (size_t)rB * CC + kB * 8);
    *(bf16x8*)&As[0][w0] = va0; *(bf16x8*)&As[0][w1] = va1;
    *(bf16x8*)&Bs[0][wB] = vb0;
    __syncthreads();

    for (int kt = 0; kt < 16; ++kt) {
        int s = kt & 1;
        if (kt < 15) {
            const __bf16* Ak = Ab + (kt + 1) * 32;
            const __bf16* Bk = Bb + (kt + 1) * 32;
            va0 = *(const bf16x8*)(Ak + (size_t)r0 * CC + k0c * 8);
            va1 = *(const bf16x8*)(Ak + (size_t)r1 * CC + k1c * 8);
            vb0 = *(const bf16x8*)(Bk + (size_t)rB * CC + kB * 8);
        }
        bf16x8 af[2], bg[4];
#pragma unroll
        for (int f = 0; f < 2; ++f) {
            int ra = wave * 32 + f * 16 + (lane & 15);
            af[f] = *(const bf16x8*)&As[s][ra * 32 + (((lane >> 4) ^ ((ra >> 1) & 3))) * 8];
        }
#pragma unroll
        for (int f = 0; f < 4; ++f) {
            int rb = f * 16 + (lane & 15);
            bg[f] = *(const bf16x8*)&Bs[s][rb * 32 + (((lane >> 4) ^ ((rb >> 1) & 3))) * 8];
        }
#pragma unroll
        for (int i = 0; i < 2; ++i)
#pragma unroll
            for (int j = 0; j < 4; ++j)
                acc[i][j] = __builtin_amdgcn_mfma_f32_16x16x32_bf16(af[i], bg[j], acc[i][j], 0, 0, 0);
        if (kt < 15) {
            *(bf16x8*)&As[s ^ 1][w0] = va0; *(bf16x8*)&As[s ^ 1][w1] = va1;
            *(bf16x8*)&Bs[s ^ 1][wB] = vb0;
        }
        __syncthreads();
    }

    // softmax over k=64 per row; each row owned by 16 lanes (same lane>>4 group)
    int gq = lane >> 4, ln = lane & 15;
    float zp[4] = {0.f, 0.f, 0.f, 0.f};
#pragma unroll
    for (int mf = 0; mf < 2; ++mf) {
#pragma unroll
        for (int r = 0; r < 4; ++r) {
            float mx = fmaxf(fmaxf(acc[mf][0][r], acc[mf][1][r]),
                             fmaxf(acc[mf][2][r], acc[mf][3][r]));
            mx = fmaxf(mx, __shfl_xor(mx, 1));
            mx = fmaxf(mx, __shfl_xor(mx, 2));
            mx = fmaxf(mx, __shfl_xor(mx, 4));
            mx = fmaxf(mx, __shfl_xor(mx, 8));
            float e[4];
            float ssum = 0.f;
#pragma unroll
            for (int nf = 0; nf < 4; ++nf) { e[nf] = expf(acc[mf][nf][r] - mx); ssum += e[nf]; }
            ssum += __shfl_xor(ssum, 1);
            ssum += __shfl_xor(ssum, 2);
            ssum += __shfl_xor(ssum, 4);
            ssum += __shfl_xor(ssum, 8);
            float inv = 1.0f / ssum;
            int n_loc = wave * 32 + mf * 16 + gq * 4 + r;
#pragma unroll
            for (int nf = 0; nf < 4; ++nf) {
                float zv = e[nf] * inv;
                zp[nf] += zv;
                ZL[nf * 16 + ln][n_loc] = (__bf16)zv;
            }
        }
    }
#pragma unroll
    for (int nf = 0; nf < 4; ++nf) {
        float t = zp[nf];
        t += __shfl_xor(t, 16);
        t += __shfl_xor(t, 32);
        if (lane < 16) atomicAdd(&ZSUM[b * KK + nf * 16 + ln], t);
    }
    __syncthreads();
    // coalesced ZT writeout: 64 k-rows x 128 n, bf16x8 chunks
#pragma unroll
    for (int p = 0; p < 4; ++p) {
        int ci = tid + p * 256;
        int kr = ci >> 4, ch = (ci & 15) * 8;
        bf16x8 v = *(const bf16x8*)&ZL[kr][ch];
        *(bf16x8*)&ZT[((size_t)b * KK + kr) * NN + n0 + ch] = v;
    }
    // Z[n][k] writeout only when consumed (last EM iteration)
    if (write_z) {
#pragma unroll
        for (int p = 0; p < 4; ++p) {
            int idx = tid + p * 256;
            int row = idx >> 3, k8 = (idx & 7) * 8;
            bf16x8 o;
#pragma unroll
            for (int j = 0; j < 8; ++j) o[j] = ZL[k8 + j][row];
            *(bf16x8*)&Z[((size_t)b * NN + n0 + row) * KK + k8] = o;
        }
    }
}

// ---------------- muacc: MUACC[c][k] += sum_n XFC[c][n]·ZT[k][n], split-K over n ----------------
__global__ __launch_bounds__(256) void k_muacc_mfma(
    const __bf16* __restrict__ XFC, const __bf16* __restrict__ ZT,
    float* __restrict__ MUACC) {
    __shared__ __bf16 As[2][128 * 32];
    __shared__ __bf16 Bs[2][64 * 32];
    int tid = threadIdx.x;
    int lane = tid & 63, wave = tid >> 6;
    int wm = wave >> 1, wn = wave & 1;
    int c0 = (blockIdx.x & 3) * 128, sp = blockIdx.x >> 2, b = blockIdx.y;
    size_t nbase = (size_t)sp * 512;
    const __bf16* Ab = XFC + ((size_t)b * CC + c0) * NN + nbase;
    const __bf16* Bb = ZT + (size_t)b * KK * NN + nbase;

    f32x4 acc[4][2];
#pragma unroll
    for (int i = 0; i < 4; ++i)
#pragma unroll
        for (int j = 0; j < 2; ++j) acc[i][j] = f32x4{0.f, 0.f, 0.f, 0.f};

    int r0 = tid >> 2, k0c = tid & 3;
    int r1 = (tid + 256) >> 2, k1c = tid & 3;
    int w0 = r0 * 32 + (k0c ^ ((r0 >> 1) & 3)) * 8;
    int w1 = r1 * 32 + (k1c ^ ((r1 >> 1) & 3)) * 8;
    int rB = tid >> 2, kB = tid & 3;
    int wB = rB * 32 + (kB ^ ((rB >> 1) & 3)) * 8;

    bf16x8 va0, va1, vb0;
    va0 = *(const bf16x8*)(Ab + (size_t)r0 * NN + k0c * 8);
    va1 = *(const bf16x8*)(Ab + (size_t)r1 * NN + k1c * 8);
    vb0 = *(const bf16x8*)(Bb + (size_t)rB * NN + kB * 8);
    *(bf16x8*)&As[0][w0] = va0; *(bf16x8*)&As[0][w1] = va1;
    *(bf16x8*)&Bs[0][wB] = vb0;
    __syncthreads();

    for (int kt = 0; kt < 16; ++kt) {
        int s = kt & 1;
        if (kt < 15) {
            const __bf16* Ak = Ab + (kt + 1) * 32;
            const __bf16* Bk = Bb + (kt + 1) * 32;
            va0 = *(const bf16x8*)(Ak + (size_t)r0 * NN + k0c * 8);
            va1 = *(const bf16x8*)(Ak + (size_t)r1 * NN + k1c * 8);
            vb0 = *(const bf16x8*)(Bk + (size_t)rB * NN + kB * 8);
        }
        bf16x8 af[4], bg[2];
#pragma unroll
        for (int f = 0; f < 4; ++f) {
            int ra = wm * 64 + f * 16 + (lane & 15);
            af[f] = *(const bf16x8*)&As[s][ra * 32 + (((lane >> 4) ^ ((ra >> 1) & 3))) * 8];
        }
#pragma unroll
        for (int f = 0; f < 2; ++f) {
            int rb = wn * 32 + f * 16 + (lane & 15);
            bg[f] = *(const bf16x8*)&Bs[s][rb * 32 + (((lane >> 4) ^ ((rb >> 1) & 3))) * 8];
        }
#pragma unroll
        for (int i = 0; i < 4; ++i)
#pragma unroll
            for (int j = 0; j < 2; ++j)
                acc[i][j] = __builtin_amdgcn_mfma_f32_16x16x32_bf16(af[i], bg[j], acc[i][j], 0, 0, 0);
        if (kt < 15) {
            *(bf16x8*)&As[s ^ 1][w0] = va0; *(bf16x8*)&As[s ^ 1][w1] = va1;
            *(bf16x8*)&Bs[s ^ 1][wB] = vb0;
        }
        __syncthreads();
    }

    int gq = lane >> 4, ln = lane & 15;
#pragma unroll
    for (int mf = 0; mf < 4; ++mf) {
#pragma unroll
        for (int r = 0; r < 4; ++r) {
            int row = wm * 64 + mf * 16 + gq * 4 + r;
#pragma unroll
            for (int nf = 0; nf < 2; ++nf) {
                int col = wn * 32 + nf * 16 + ln;
                atomicAdd(&MUACC[((size_t)b * CC + c0 + row) * KK + col], acc[mf][nf][r]);
            }
        }
    }
}

// ---------------- munorm -> bf16 mu (both layouts); re-zeroes MUACC/ZSUM for next iter ----------------
__global__ __launch_bounds__(64) void k_munorm_bf(
    float* __restrict__ MUACC, float* __restrict__ ZSUM,
    __bf16* __restrict__ mu_bf, __bf16* __restrict__ muT_bf) {
    int k = blockIdx.x;
    int b = blockIdx.y;
    int lane = threadIdx.x;
    float scale = 1.0f / (1e-6f + ZSUM[b * KK + k]);
    float v[8];
    float ss = 0.f;
#pragma unroll
    for (int i = 0; i < 8; ++i) {
        size_t a = (size_t)b * CC * KK + (size_t)(lane + i * 64) * KK + k;
        v[i] = MUACC[a] * scale;
        MUACC[a] = 0.f;               // re-zero for the next EM iteration
        ss += v[i] * v[i];
    }
    if (lane == 0) ZSUM[b * KK + k] = 0.f;
    for (int off = 32; off; off >>= 1) ss += __shfl_xor(ss, off);
    float nrm = 1.0f / (1e-6f + sqrtf(ss));
#pragma unroll
    for (int i = 0; i < 8; ++i) {
        int c = lane + i * 64;
        __bf16 o = (__bf16)(v[i] * nrm);
        mu_bf[((size_t)b * CC + c) * KK + k] = o;
        muT_bf[((size_t)b * KK + k) * CC + c] = o;
    }
}

// ---------------- xr: XRT[b][n][c] = bf16(relu( sum_k Z[n][k]·mu[c][k] )), K=64 ----------------
__global__ __launch_bounds__(256) void k_xr_mfma(
    const __bf16* __restrict__ Zm, const __bf16* __restrict__ MUB,
    __bf16* __restrict__ XRT) {
    __shared__ __bf16 SM[17408];    // As(8192)+Bs(8192); aliased by TT[128][136]
    __bf16* As = SM;
    __bf16* Bs = SM + 8192;
    int tid = threadIdx.x;
    int lane = tid & 63, wave = tid >> 6;
    int wm = wave >> 1, wn = wave & 1;
    int n0 = blockIdx.x * 128, c0 = blockIdx.y * 128, b = blockIdx.z;
    const __bf16* Ab = Zm + ((size_t)b * NN + n0) * KK;
    const __bf16* Bb = MUB + ((size_t)b * CC + c0) * KK;
#pragma unroll
    for (int p = 0; p < 4; ++p) {
        int idx = tid + p * 256;
        int r = idx >> 3, ch = idx & 7;
        int woff = r * 64 + ((ch ^ (r & 7)) * 8);
        *(bf16x8*)&As[woff] = *(const bf16x8*)(Ab + (size_t)r * KK + ch * 8);
        *(bf16x8*)&Bs[woff] = *(const bf16x8*)(Bb + (size_t)r * KK + ch * 8);
    }
    __syncthreads();

    f32x4 acc[4][4];
#pragma unroll
    for (int i = 0; i < 4; ++i)
#pragma unroll
        for (int j = 0; j < 4; ++j) acc[i][j] = f32x4{0.f, 0.f, 0.f, 0.f};

    int gq = lane >> 4, ln = lane & 15;
#pragma unroll
    for (int ks = 0; ks < 2; ++ks) {
        bf16x8 af[4], bg[4];
#pragma unroll
        for (int f = 0; f < 4; ++f) {
            int ra = wm * 64 + f * 16 + ln;
            af[f] = *(const bf16x8*)&As[ra * 64 + (((ks * 4 + gq) ^ (ra & 7))) * 8];
            int rb = wn * 64 + f * 16 + ln;
            bg[f] = *(const bf16x8*)&Bs[rb * 64 + (((ks * 4 + gq) ^ (rb & 7))) * 8];
        }
#pragma unroll
        for (int i = 0; i < 4; ++i)
#pragma unroll
            for (int j = 0; j < 4; ++j)
                acc[i][j] = __builtin_amdgcn_mfma_f32_16x16x32_bf16(af[i], bg[j], acc[i][j], 0, 0, 0);
    }
    __syncthreads();   // all As/Bs reads done before TT alias writes

    __bf16* TT = SM;   // TT[128n][136]
#pragma unroll
    for (int mf = 0; mf < 4; ++mf) {
#pragma unroll
        for (int nf = 0; nf < 4; ++nf) {
            int c_loc = wn * 64 + nf * 16 + ln;
            int n_loc4 = wm * 64 + mf * 16 + gq * 4;
#pragma unroll
            for (int r = 0; r < 4; ++r)
                TT[(n_loc4 + r) * 136 + c_loc] = (__bf16)fmaxf(acc[mf][nf][r], 0.f);
        }
    }
    __syncthreads();
#pragma unroll
    for (int p = 0; p < 8; ++p) {
        int idx = tid + p * 256;
        int row = idx >> 4, ch = idx & 15;
        bf16x8 v = *(const bf16x8*)&TT[row * 136 + ch * 8];
        *(bf16x8*)&XRT[((size_t)b * NN + n0 + row) * CC + c0 + ch * 8] = v;
    }
}

extern "C" void kernel_launch(void* const* d_in, const int* in_sizes, int n_in,
                              void* d_out, int out_size, void* d_ws, size_t ws_size,
                              hipStream_t stream) {
    const float* x     = (const float*)d_in[0];
    const float* w1    = (const float*)d_in[1];
    const float* b1    = (const float*)d_in[2];
    const float* mu_in = (const float*)d_in[3];
    const float* w2    = (const float*)d_in[4];
    const float* gamma = (const float*)d_in[5];
    const float* beta  = (const float*)d_in[6];
    const float* mean  = (const float*)d_in[7];
    const float* var   = (const float*)d_in[8];
    float* out = (float*)d_out;
    float* ws  = (float*)d_ws;

    __bf16* xt    = (__bf16*)(ws + R1_OFF);
    __bf16* xft   = (__bf16*)(ws + R2_OFF);    // region 2: XFT, later XRT
    __bf16* xrt   = (__bf16*)(ws + R2_OFF);
    __bf16* xfc   = (__bf16*)d_out;            // XFC staged in d_out (dead until conv2 writes)
    __bf16* zbf   = (__bf16*)(ws + Z_OFF);
    __bf16* ztbf  = (__bf16*)(ws + ZT_OFF);
    float*  muacc = ws + MUACC_OFF;
    float*  zsum  = ws + ZSUM_OFF;
    __bf16* mu_bf = (__bf16*)(ws + MUBF_OFF);
    __bf16* muT_bf= (__bf16*)(ws + MUTBF_OFF);
    __bf16* w1bf  = (__bf16*)(ws + W1BF_OFF);
    __bf16* w2bf  = (__bf16*)(ws + W2BF_OFF);

    // one memset covers MUACC+ZSUM (contiguous); k_munorm_bf re-zeroes them each iter
    hipMemsetAsync(muacc, 0, (size_t)(BB * CC * KK + BB * KK) * sizeof(float), stream);
    hipLaunchKernelGGL(k_cvt2, dim3(256), dim3(256), 0, stream, w1, w2, w1bf, w2bf);
    hipLaunchKernelGGL(k_mu_bcast_bf, dim3(128), dim3(256), 0, stream, mu_in, mu_bf, muT_bf);
    hipLaunchKernelGGL(k_xpose_cvt, dim3(NN / 64, CC / 64, BB), dim3(256), 0, stream, x, xt);
    hipLaunchKernelGGL(k_conv1_mfma, dim3(CC / 128, NN / 128, BB), dim3(256), 0, stream,
                       xt, w1bf, b1, xft, xfc);
    for (int it = 0; it < 3; ++it) {
        hipLaunchKernelGGL(k_zsoftmax_mfma, dim3(NN / 128, BB), dim3(256), 0, stream,
                           xft, muT_bf, zbf, ztbf, zsum, (it == 2) ? 1 : 0);
        hipLaunchKernelGGL(k_muacc_mfma, dim3(32, BB), dim3(256), 0, stream, xfc, ztbf, muacc);
        hipLaunchKernelGGL(k_munorm_bf, dim3(KK, BB), dim3(64), 0, stream, muacc, zsum,
                           mu_bf, muT_bf);
    }
    hipLaunchKernelGGL(k_xr_mfma, dim3(NN / 128, CC / 128, BB), dim3(256), 0, stream,
                       zbf, mu_bf, xrt);
    hipLaunchKernelGGL(k_conv2_mfma, dim3(NN / 128, CC / 128, BB), dim3(256), 0, stream,
                       w2bf, xrt, gamma, beta, mean, var, x, out);
}